// Round 3
// baseline (753.352 us; speedup 1.0000x reference)
//
#include <hip/hip_runtime.h>
#include <cmath>

#define BB 32
#define NN 4096
#define NC 37
#define C1 36
#define KK 100
#define DD 512
#define SCORE_TH 0.1f
#define NMS_TH 0.4f
#define NBC (BB * C1)      // 1152
#define GCAP 4096          // per-(b,c) candidate capacity (hard bound: N=4096)
#define LCAP 2048          // LDS sort capacity (chunked fallback keeps exactness beyond this)
#define NT 256

// ---------------- K0: zero the per-(b,c) counters (capture-safe, no memset API)
__global__ __launch_bounds__(256) void zero_kernel(int* __restrict__ gcnt)
{
    const int t = blockIdx.x * 256 + threadIdx.x;
    if (t < NBC) gcnt[t] = 0;
}

// ---------------- K1: coalesced threshold scatter ----------------
// One thread per score element. Fully coalesced 19.4 MB read; passing
// elements scatter a sortable key into the per-(b,c) workspace list.
__global__ __launch_bounds__(256) void scatter_kernel(
    const float* __restrict__ scores,          // B,N,C
    int* __restrict__ gcnt,                    // NBC
    unsigned long long* __restrict__ gcand)    // NBC x GCAP
{
    const int t = blockIdx.x * 256 + threadIdx.x;
    const int TOT = BB * NN * NC;              // 4,849,664
    if (t >= TOT) return;
    float v = scores[t];
    int c = t % NC;
    if (c == 0) return;                        // background class
    if (v > SCORE_TH) {
        int bn = t / NC;
        int b = bn / NN;
        int n = bn % NN;
        int bc = b * C1 + (c - 1);
        int pos = atomicAdd(&gcnt[bc], 1);     // pos < 4096 guaranteed (n-range)
        unsigned int vb = __float_as_uint(v);  // v>0.1 => positive => uint order == float order
        gcand[(size_t)bc * GCAP + pos] =
            ((unsigned long long)vb << 32) | (unsigned int)(0xFFFFFFFFu - (unsigned int)n);
    }
}

// ---------------- K2: per-(b,c) sort -> decode -> NMS -> emit ----------------
__global__ __launch_bounds__(NT) void detect_kernel(
    const float* __restrict__ boxes,      // B,N,4
    const float* __restrict__ deltas,     // B,N,4*C
    const float* __restrict__ feats,      // B,N,D
    const float* __restrict__ im_info,    // B,3
    const int* __restrict__ gcnt,
    const unsigned long long* __restrict__ gcand,
    float* __restrict__ out)              // NBC*KK x 517
{
#pragma clang fp contract(off)
    __shared__ unsigned long long cand[LCAP];      // 16 KB
    __shared__ float sbox[KK][4];
    __shared__ float sarea[KK];
    __shared__ float sval[KK];
    __shared__ int   sidx[KK];
    __shared__ int   skeep[KK];
    __shared__ unsigned int smeta[KK];

    const int bc  = blockIdx.x;
    const int b   = bc / C1;
    const int c   = bc % C1;              // output class c -> source class c+1
    const int tid = threadIdx.x;

    const int M = gcnt[bc];
    const unsigned long long* src = gcand + (size_t)bc * GCAP;

    // ---- Phase A: load candidates (coalesced), chunked exact top-K sort.
    // Typical M ~ 200 => single chunk, P=256. Fallback (M > LCAP) merges
    // chunks through the running top-KK prefix — exact for any M <= GCAP.
    int take = M < LCAP ? M : LCAP;
    for (int i = tid; i < take; i += NT) cand[i] = src[i];
    int consumed = take;
    int total    = take;

    for (;;) {
        int P = 128; while (P < total) P <<= 1;            // <= LCAP
        for (int i = total + tid; i < P; i += NT) cand[i] = 0ULL;
        __syncthreads();
        // bitonic sort descending (value desc, index asc on ties via ~n in key)
        for (int k = 2; k <= P; k <<= 1) {
            for (int j = k >> 1; j > 0; j >>= 1) {
                for (int i = tid; i < P; i += NT) {
                    int ixj = i ^ j;
                    if (ixj > i) {
                        unsigned long long a  = cand[i];
                        unsigned long long bb = cand[ixj];
                        bool desc = ((i & k) == 0);
                        if (desc ? (a < bb) : (a > bb)) {
                            cand[i]   = bb;
                            cand[ixj] = a;
                        }
                    }
                }
                __syncthreads();
            }
        }
        if (consumed >= M) break;
        int t2 = M - consumed;
        if (t2 > LCAP - KK) t2 = LCAP - KK;
        for (int i = tid; i < t2; i += NT) cand[KK + i] = src[consumed + i];
        consumed += t2;
        total = KK + t2;
        __syncthreads();
    }

    const int V = (M < KK) ? M : KK;

    // ---- Phase C: decode + clip + scale (exact ref op order)
    if (tid < KK) {
        int k = tid;
        if (k < V) {
            unsigned long long key = cand[k];
            float v = __uint_as_float((unsigned int)(key >> 32));
            int   n = (int)(0xFFFFFFFFu - (unsigned int)(key & 0xFFFFFFFFull));
            sval[k] = v;
            sidx[k] = n;
            skeep[k] = 1;

            const float* bp = boxes + (b * NN + n) * 4;
            float bx1 = bp[0], by1 = bp[1], bx2 = bp[2], by2 = bp[3];
            const float* dp = deltas + ((b * NN + n) * NC + (c + 1)) * 4;
            float d0 = dp[0] * 0.1f;
            float d1 = dp[1] * 0.1f;
            float d2 = dp[2] * 0.2f;
            float d3 = dp[3] * 0.2f;

            float w  = bx2 - bx1 + 1.0f;
            float h  = by2 - by1 + 1.0f;
            float cx = bx1 + 0.5f * w;
            float cy = by1 + 0.5f * h;
            float pcx = d0 * w + cx;
            float pcy = d1 * h + cy;
            float pw  = (float)exp((double)d2) * w;   // correctly-rounded f32 exp
            float ph  = (float)exp((double)d3) * h;

            float hmax = im_info[b * 3 + 0] - 1.0f;
            float wmax = im_info[b * 3 + 1] - 1.0f;
            float sc   = im_info[b * 3 + 2];

            float x1p = fminf(fmaxf(pcx - 0.5f * pw, 0.0f), wmax);
            float y1p = fminf(fmaxf(pcy - 0.5f * ph, 0.0f), hmax);
            float x2p = fminf(fmaxf(pcx + 0.5f * pw, 0.0f), wmax);
            float y2p = fminf(fmaxf(pcy + 0.5f * ph, 0.0f), hmax);
            x1p = x1p / sc; y1p = y1p / sc; x2p = x2p / sc; y2p = y2p / sc;

            sbox[k][0] = x1p; sbox[k][1] = y1p; sbox[k][2] = x2p; sbox[k][3] = y2p;
            sarea[k] = (x2p - x1p) * (y2p - y1p);
        } else {
            sval[k] = 0.0f; sidx[k] = 0; skeep[k] = 0;
            sbox[k][0] = sbox[k][1] = sbox[k][2] = sbox[k][3] = 0.0f;
            sarea[k] = 0.0f;
        }
    }
    __syncthreads();

    // ---- Phase D: greedy NMS in ONE wave, zero barriers.
    // Lane ln owns boxes {ln, 64+ln}; keep bits live in registers; box i is
    // broadcast via shfl. Greedy semantics identical to ref fori_loop.
    if (tid < 64) {
        const int ln = tid;
        float ax1 = sbox[ln][0], ay1 = sbox[ln][1], ax2 = sbox[ln][2], ay2 = sbox[ln][3];
        float aar = sarea[ln];
        int   ka  = (ln < V) ? 1 : 0;
        float bx1 = 0.f, by1 = 0.f, bx2 = 0.f, by2 = 0.f, bar = 0.f;
        int   kb  = 0;
        if (ln < KK - 64) {
            bx1 = sbox[64 + ln][0]; by1 = sbox[64 + ln][1];
            bx2 = sbox[64 + ln][2]; by2 = sbox[64 + ln][3];
            bar = sarea[64 + ln];
            kb  = (64 + ln < V) ? 1 : 0;
        }
        for (int i = 0; i < V; ++i) {
            const int  srcl = i & 63;
            const bool hi   = (i >= 64);
            int ki = __shfl(hi ? kb : ka, srcl);
            if (ki) {
                float ix1 = __shfl(hi ? bx1 : ax1, srcl);
                float iy1 = __shfl(hi ? by1 : ay1, srcl);
                float ix2 = __shfl(hi ? bx2 : ax2, srcl);
                float iy2 = __shfl(hi ? by2 : ay2, srcl);
                float iar = __shfl(hi ? bar : aar, srcl);
                if (ka && ln > i) {
                    float ltx = fmaxf(ix1, ax1);
                    float lty = fmaxf(iy1, ay1);
                    float rbx = fminf(ix2, ax2);
                    float rby = fminf(iy2, ay2);
                    float iw = fmaxf(rbx - ltx, 0.0f);
                    float ih = fmaxf(rby - lty, 0.0f);
                    float inter = iw * ih;
                    float denom = iar + aar;
                    denom = denom - inter;
                    denom = denom + 1e-8f;
                    if (inter / denom > NMS_TH) ka = 0;
                }
                if (kb && 64 + ln > i) {
                    float ltx = fmaxf(ix1, bx1);
                    float lty = fmaxf(iy1, by1);
                    float rbx = fminf(ix2, bx2);
                    float rby = fminf(iy2, by2);
                    float iw = fmaxf(rbx - ltx, 0.0f);
                    float ih = fmaxf(rby - lty, 0.0f);
                    float inter = iw * ih;
                    float denom = iar + bar;
                    denom = denom - inter;
                    denom = denom + 1e-8f;
                    if (inter / denom > NMS_TH) kb = 0;
                }
            }
        }
        skeep[ln] = ka;
        if (ln < KK - 64) skeep[64 + ln] = kb;
    }
    __syncthreads();

    // ---- Phase E0: meta + heads (5 floats/row) in parallel.
    const long long bcbase = (long long)bc * (KK * 517);
    for (int e = tid; e < KK; e += NT)
        smeta[e] = skeep[e] ? (0x80000000u | (unsigned)sidx[e]) : 0u;  // dead rows -> n=0 (cache-hot)
    for (int e = tid; e < KK * 5; e += NT) {
        int k = e / 5, j = e - k * 5;
        float hv = (j < 4) ? sbox[k][j] : sval[k];
        if (!skeep[k]) hv = 0.0f;
        __builtin_nontemporal_store(hv, out + bcbase + (long long)k * 517 + j);
    }
    __syncthreads();

    // ---- Phase E1: feats copy, one wave per row, meta broadcast from
    // registers (no LDS / branch dependency in the loop -> pipelines).
    const int wv = tid >> 6;
    const int ln = tid & 63;
    const int k0 = wv * 25;                       // 4 waves x 25 rows = 100
    int mym = (ln < 25) ? (int)smeta[k0 + ln] : 0;
    const float* fbase = feats + (long long)b * NN * DD;
#pragma unroll 2
    for (int t = 0; t < 25; ++t) {
        unsigned int m = (unsigned int)__shfl(mym, t);
        const int  n  = (int)(m & 0x7FFFFFFFu);
        const bool kp = (m & 0x80000000u) != 0u;
        const float4* f4 = (const float4*)(fbase + (long long)n * DD);
        float4 v0 = f4[ln];
        float4 v1 = f4[ln + 64];
        if (!kp) {
            v0.x = v0.y = v0.z = v0.w = 0.0f;
            v1.x = v1.y = v1.z = v1.w = 0.0f;
        }
        float* o5 = out + bcbase + (long long)(k0 + t) * 517 + 5;
        const int j0 = ln * 4;
        __builtin_nontemporal_store(v0.x, o5 + j0 + 0);
        __builtin_nontemporal_store(v0.y, o5 + j0 + 1);
        __builtin_nontemporal_store(v0.z, o5 + j0 + 2);
        __builtin_nontemporal_store(v0.w, o5 + j0 + 3);
        const int j1 = (ln + 64) * 4;
        __builtin_nontemporal_store(v1.x, o5 + j1 + 0);
        __builtin_nontemporal_store(v1.y, o5 + j1 + 1);
        __builtin_nontemporal_store(v1.z, o5 + j1 + 2);
        __builtin_nontemporal_store(v1.w, o5 + j1 + 3);
    }
}

extern "C" void kernel_launch(void* const* d_in, const int* in_sizes, int n_in,
                              void* d_out, int out_size, void* d_ws, size_t ws_size,
                              hipStream_t stream) {
    const float* boxes    = (const float*)d_in[0];
    const float* deltas   = (const float*)d_in[1];
    const float* scores   = (const float*)d_in[2];
    const float* feats    = (const float*)d_in[3];
    const float* im_info  = (const float*)d_in[4];
    float* out = (float*)d_out;

    // workspace layout
    char* ws = (char*)d_ws;
    int* gcnt = (int*)ws;                               // NBC ints
    unsigned long long* gcand =
        (unsigned long long*)(ws + 8192);               // NBC x GCAP keys (37.7 MB)

    zero_kernel<<<dim3((NBC + 255) / 256), dim3(256), 0, stream>>>(gcnt);

    const int TOT = BB * NN * NC;
    scatter_kernel<<<dim3((TOT + 255) / 256), dim3(256), 0, stream>>>(scores, gcnt, gcand);
    detect_kernel<<<dim3(NBC), dim3(NT), 0, stream>>>(
        boxes, deltas, feats, im_info, gcnt, gcand, out);
}

// Round 4
// 536.084 us; speedup vs baseline: 1.4053x; 1.4053x over previous
//
#include <hip/hip_runtime.h>
#include <cmath>

#define BB 32
#define NN 4096
#define NC 37
#define C1 36
#define KK 100
#define DD 512
#define SCORE_TH 0.1f
#define NMS_TH 0.4f
#define NBC (BB * C1)      // 1152
#define LCAP 2048          // LDS sort capacity
#define OCAP 2048          // per-(b,c) overflow capacity (LCAP+OCAP = N, exact)
#define NT 256

// ---------------- K1: class-major transpose of scores ----------------
// scoresT[b][c1][n] = scores[b][n][c1+1]; gives detect blocks a contiguous
// 16 KB class row. No atomics anywhere.
__global__ __launch_bounds__(256) void transpose_kernel(
    const float* __restrict__ scores,     // B,N,C
    float* __restrict__ scoresT)          // NBC x NN
{
    __shared__ float tile[37 * 65];       // [c][i], stride 65 kills bank conflicts

    const int b  = blockIdx.x >> 6;              // 32 b
    const int t0 = (blockIdx.x & 63) * 64;       // 64 n-tiles of 64
    const int tid = threadIdx.x;

    const float4* src4 = (const float4*)(scores + ((size_t)b * NN + t0) * NC);
    for (int q = tid; q < (64 * 37) / 4; q += 256) {     // 592 float4
        float4 v = src4[q];
        int e = q * 4;
        #pragma unroll
        for (int u = 0; u < 4; ++u) {
            int i = (e + u) / 37;
            int c = (e + u) - i * 37;
            float x = (u == 0) ? v.x : (u == 1) ? v.y : (u == 2) ? v.z : v.w;
            tile[c * 65 + i] = x;
        }
    }
    __syncthreads();

    float* dst = scoresT + (size_t)b * C1 * NN + t0;
    for (int q = tid; q < 36 * 16; q += 256) {           // 16 float4 per class row
        int c1 = q >> 4;
        int i4 = (q & 15) * 4;
        float4 v;
        v.x = tile[(c1 + 1) * 65 + i4 + 0];
        v.y = tile[(c1 + 1) * 65 + i4 + 1];
        v.z = tile[(c1 + 1) * 65 + i4 + 2];
        v.w = tile[(c1 + 1) * 65 + i4 + 3];
        *(float4*)(dst + (size_t)c1 * NN + i4) = v;
    }
}

// ---------------- K2: per-(b,c) threshold -> sort -> decode -> NMS -> emit ----
__global__ __launch_bounds__(NT) void detect_kernel(
    const float* __restrict__ boxes,      // B,N,4
    const float* __restrict__ deltas,     // B,N,4*C
    const float* __restrict__ feats,      // B,N,D
    const float* __restrict__ im_info,    // B,3
    const float* __restrict__ scoresT,    // NBC x NN
    unsigned long long* __restrict__ gover,  // NBC x OCAP spill (block-private)
    float* __restrict__ out)              // NBC*KK x 517
{
#pragma clang fp contract(off)
    __shared__ unsigned long long cand[LCAP];      // 16 KB
    __shared__ int scnt;
    __shared__ float sbox[KK][4];
    __shared__ float sarea[KK];
    __shared__ float sval[KK];
    __shared__ int   sidx[KK];
    __shared__ int   skeep[KK];
    __shared__ unsigned int smeta[KK];

    const int bc  = blockIdx.x;
    const int b   = bc / C1;
    const int c   = bc % C1;              // output class c -> source class c+1
    const int tid = threadIdx.x;

    if (tid == 0) scnt = 0;
    __syncthreads();

    // ---- Phase A: contiguous 16 KB class row, compact via LDS atomic.
    unsigned long long* over = gover + (size_t)bc * OCAP;
    const float4* s4 = (const float4*)(scoresT + (size_t)bc * NN);
    for (int i = tid; i < NN / 4; i += NT) {
        float4 v = s4[i];
        const int n0 = i * 4;
        #pragma unroll
        for (int u = 0; u < 4; ++u) {
            float x = (u == 0) ? v.x : (u == 1) ? v.y : (u == 2) ? v.z : v.w;
            if (x > SCORE_TH) {
                int pos = atomicAdd(&scnt, 1);
                unsigned long long key =
                    ((unsigned long long)__float_as_uint(x) << 32) |
                    (unsigned int)(0xFFFFFFFFu - (unsigned int)(n0 + u));
                if (pos < LCAP) cand[pos] = key;
                else            over[pos - LCAP] = key;   // vanishingly rare
            }
        }
    }
    __syncthreads();
    const int M = scnt;

    // ---- Phase B: chunked exact top-K bitonic sort (typical M~205 => P=256)
    int consumed = (M < LCAP) ? M : LCAP;
    int total    = consumed;
    for (;;) {
        int P = 128; while (P < total) P <<= 1;            // <= LCAP
        for (int i = total + tid; i < P; i += NT) cand[i] = 0ULL;
        __syncthreads();
        for (int k = 2; k <= P; k <<= 1) {
            for (int j = k >> 1; j > 0; j >>= 1) {
                for (int i = tid; i < P; i += NT) {
                    int ixj = i ^ j;
                    if (ixj > i) {
                        unsigned long long a  = cand[i];
                        unsigned long long bb = cand[ixj];
                        bool desc = ((i & k) == 0);
                        if (desc ? (a < bb) : (a > bb)) {
                            cand[i]   = bb;
                            cand[ixj] = a;
                        }
                    }
                }
                __syncthreads();
            }
        }
        if (consumed >= M) break;
        int t2 = M - consumed;
        if (t2 > LCAP - KK) t2 = LCAP - KK;
        for (int i = tid; i < t2; i += NT) cand[KK + i] = over[consumed - LCAP + i];
        consumed += t2;
        total = KK + t2;
        __syncthreads();
    }

    const int V = (M < KK) ? M : KK;

    // ---- Phase C: decode + clip + scale (exact ref op order)
    if (tid < KK) {
        int k = tid;
        if (k < V) {
            unsigned long long key = cand[k];
            float v = __uint_as_float((unsigned int)(key >> 32));
            int   n = (int)(0xFFFFFFFFu - (unsigned int)(key & 0xFFFFFFFFull));
            sval[k] = v;
            sidx[k] = n;
            skeep[k] = 1;

            const float* bp = boxes + (b * NN + n) * 4;
            float bx1 = bp[0], by1 = bp[1], bx2 = bp[2], by2 = bp[3];
            const float* dp = deltas + ((b * NN + n) * NC + (c + 1)) * 4;
            float d0 = dp[0] * 0.1f;
            float d1 = dp[1] * 0.1f;
            float d2 = dp[2] * 0.2f;
            float d3 = dp[3] * 0.2f;

            float w  = bx2 - bx1 + 1.0f;
            float h  = by2 - by1 + 1.0f;
            float cx = bx1 + 0.5f * w;
            float cy = by1 + 0.5f * h;
            float pcx = d0 * w + cx;
            float pcy = d1 * h + cy;
            float pw  = (float)exp((double)d2) * w;   // correctly-rounded f32 exp
            float ph  = (float)exp((double)d3) * h;

            float hmax = im_info[b * 3 + 0] - 1.0f;
            float wmax = im_info[b * 3 + 1] - 1.0f;
            float sc   = im_info[b * 3 + 2];

            float x1p = fminf(fmaxf(pcx - 0.5f * pw, 0.0f), wmax);
            float y1p = fminf(fmaxf(pcy - 0.5f * ph, 0.0f), hmax);
            float x2p = fminf(fmaxf(pcx + 0.5f * pw, 0.0f), wmax);
            float y2p = fminf(fmaxf(pcy + 0.5f * ph, 0.0f), hmax);
            x1p = x1p / sc; y1p = y1p / sc; x2p = x2p / sc; y2p = y2p / sc;

            sbox[k][0] = x1p; sbox[k][1] = y1p; sbox[k][2] = x2p; sbox[k][3] = y2p;
            sarea[k] = (x2p - x1p) * (y2p - y1p);
        } else {
            sval[k] = 0.0f; sidx[k] = 0; skeep[k] = 0;
            sbox[k][0] = sbox[k][1] = sbox[k][2] = sbox[k][3] = 0.0f;
            sarea[k] = 0.0f;
        }
    }
    __syncthreads();

    // ---- Phase D: greedy NMS in ONE wave, zero barriers (ref-equal greedy).
    if (tid < 64) {
        const int ln = tid;
        float ax1 = sbox[ln][0], ay1 = sbox[ln][1], ax2 = sbox[ln][2], ay2 = sbox[ln][3];
        float aar = sarea[ln];
        int   ka  = (ln < V) ? 1 : 0;
        float bx1 = 0.f, by1 = 0.f, bx2 = 0.f, by2 = 0.f, bar = 0.f;
        int   kb  = 0;
        if (ln < KK - 64) {
            bx1 = sbox[64 + ln][0]; by1 = sbox[64 + ln][1];
            bx2 = sbox[64 + ln][2]; by2 = sbox[64 + ln][3];
            bar = sarea[64 + ln];
            kb  = (64 + ln < V) ? 1 : 0;
        }
        for (int i = 0; i < V; ++i) {
            const int  srcl = i & 63;
            const bool hi   = (i >= 64);
            int ki = __shfl(hi ? kb : ka, srcl);
            if (ki) {
                float ix1 = __shfl(hi ? bx1 : ax1, srcl);
                float iy1 = __shfl(hi ? by1 : ay1, srcl);
                float ix2 = __shfl(hi ? bx2 : ax2, srcl);
                float iy2 = __shfl(hi ? by2 : ay2, srcl);
                float iar = __shfl(hi ? bar : aar, srcl);
                if (ka && ln > i) {
                    float ltx = fmaxf(ix1, ax1);
                    float lty = fmaxf(iy1, ay1);
                    float rbx = fminf(ix2, ax2);
                    float rby = fminf(iy2, ay2);
                    float iw = fmaxf(rbx - ltx, 0.0f);
                    float ih = fmaxf(rby - lty, 0.0f);
                    float inter = iw * ih;
                    float denom = iar + aar;
                    denom = denom - inter;
                    denom = denom + 1e-8f;
                    if (inter / denom > NMS_TH) ka = 0;
                }
                if (kb && 64 + ln > i) {
                    float ltx = fmaxf(ix1, bx1);
                    float lty = fmaxf(iy1, by1);
                    float rbx = fminf(ix2, bx2);
                    float rby = fminf(iy2, by2);
                    float iw = fmaxf(rbx - ltx, 0.0f);
                    float ih = fmaxf(rby - lty, 0.0f);
                    float inter = iw * ih;
                    float denom = iar + bar;
                    denom = denom - inter;
                    denom = denom + 1e-8f;
                    if (inter / denom > NMS_TH) kb = 0;
                }
            }
        }
        skeep[ln] = ka;
        if (ln < KK - 64) skeep[64 + ln] = kb;
    }
    __syncthreads();

    // ---- Phase E0: meta + heads (5 floats/row) in parallel.
    const long long bcbase = (long long)bc * (KK * 517);
    for (int e = tid; e < KK; e += NT)
        smeta[e] = skeep[e] ? (0x80000000u | (unsigned)sidx[e]) : 0u;  // dead rows -> n=0 (cache-hot)
    for (int e = tid; e < KK * 5; e += NT) {
        int k = e / 5, j = e - k * 5;
        float hv = (j < 4) ? sbox[k][j] : sval[k];
        if (!skeep[k]) hv = 0.0f;
        __builtin_nontemporal_store(hv, out + bcbase + (long long)k * 517 + j);
    }
    __syncthreads();

    // ---- Phase E1: feats copy, one wave per row, meta broadcast from regs.
    const int wv = tid >> 6;
    const int ln = tid & 63;
    const int k0 = wv * 25;                       // 4 waves x 25 rows = 100
    int mym = (ln < 25) ? (int)smeta[k0 + ln] : 0;
    const float* fbase = feats + (long long)b * NN * DD;
#pragma unroll 2
    for (int t = 0; t < 25; ++t) {
        unsigned int m = (unsigned int)__shfl(mym, t);
        const int  n  = (int)(m & 0x7FFFFFFFu);
        const bool kp = (m & 0x80000000u) != 0u;
        const float4* f4 = (const float4*)(fbase + (long long)n * DD);
        float4 v0 = f4[ln];
        float4 v1 = f4[ln + 64];
        if (!kp) {
            v0.x = v0.y = v0.z = v0.w = 0.0f;
            v1.x = v1.y = v1.z = v1.w = 0.0f;
        }
        float* o5 = out + bcbase + (long long)(k0 + t) * 517 + 5;
        const int j0 = ln * 4;
        __builtin_nontemporal_store(v0.x, o5 + j0 + 0);
        __builtin_nontemporal_store(v0.y, o5 + j0 + 1);
        __builtin_nontemporal_store(v0.z, o5 + j0 + 2);
        __builtin_nontemporal_store(v0.w, o5 + j0 + 3);
        const int j1 = (ln + 64) * 4;
        __builtin_nontemporal_store(v1.x, o5 + j1 + 0);
        __builtin_nontemporal_store(v1.y, o5 + j1 + 1);
        __builtin_nontemporal_store(v1.z, o5 + j1 + 2);
        __builtin_nontemporal_store(v1.w, o5 + j1 + 3);
    }
}

extern "C" void kernel_launch(void* const* d_in, const int* in_sizes, int n_in,
                              void* d_out, int out_size, void* d_ws, size_t ws_size,
                              hipStream_t stream) {
    const float* boxes    = (const float*)d_in[0];
    const float* deltas   = (const float*)d_in[1];
    const float* scores   = (const float*)d_in[2];
    const float* feats    = (const float*)d_in[3];
    const float* im_info  = (const float*)d_in[4];
    float* out = (float*)d_out;

    // workspace layout
    char* ws = (char*)d_ws;
    float* scoresT = (float*)ws;                                   // NBC*NN floats (18.9 MB)
    unsigned long long* gover =
        (unsigned long long*)(ws + (size_t)NBC * NN * sizeof(float));  // NBC*OCAP (18.9 MB)

    transpose_kernel<<<dim3(BB * 64), dim3(256), 0, stream>>>(scores, scoresT);
    detect_kernel<<<dim3(NBC), dim3(NT), 0, stream>>>(
        boxes, deltas, feats, im_info, scoresT, gover, out);
}